// Round 1
// baseline (177.456 us; speedup 1.0000x reference)
//
#include <hip/hip_runtime.h>

// TDT loss, fixed shapes from setup_inputs():
#define TDT_B  8
#define TDT_T  256
#define TDT_U  64
#define TDT_U1 65
#define TDT_V1 513   // V+1, blank index = 512
#define TP     275   // 4 NEG pad slices + 256 + 15 FIFO slack
#define NEGV  (-1e30f)
#define SIG    0.05f

// ws layout (floats):
//   PBD: float4[B][TP][U1]  = lpb(b,tau,u) + ld(b,tau,u,i)   (i in .x..w)
//   PYD: float4[B][TP][U]   = lpy(b,tau,u) + ld(b,tau,u,i)
//   LL : float[B]
#define OFF_PYD (TDT_B * TP * TDT_U1 * 4)            // 572000
#define OFF_LL  (OFF_PYD + TDT_B * TP * TDT_U * 4)   // 1135200

__device__ __forceinline__ float lse4(float x0, float x1, float x2, float x3) {
  float m = fmaxf(fmaxf(x0, x1), fmaxf(x2, x3));
  float s = __expf(x0 - m) + __expf(x1 - m) + __expf(x2 - m) + __expf(x3 - m);
  return m + __logf(s);
}
__device__ __forceinline__ float lae(float x, float y) {
  float m = fmaxf(x, y);
  return m + __logf(__expf(x - m) + __expf(y - m));
}

// Kernel 1: per-(b,t,u) row log-softmax over 513 labels (wave per row),
// duration log-softmax over 4, write combined PBD/PYD float4 records.
__global__ __launch_bounds__(256) void k_prep(
    const float* __restrict__ la, const float* __restrict__ da,
    const int* __restrict__ tgt, float* __restrict__ ws)
{
  const int l = threadIdx.x & 63;
  const int r = (blockIdx.x << 2) + (threadIdx.x >> 6);   // row in [0, B*T*U1)
  const int u  = r % TDT_U1;
  const int bt = r / TDT_U1;
  const int t  = bt & (TDT_T - 1);
  const int b  = bt >> 8;

  const float* row = la + (long)r * TDT_V1;
  float v[8];
#pragma unroll
  for (int k = 0; k < 8; ++k) v[k] = row[l + (k << 6)];
  const float xb = (l == 0) ? row[512] : NEGV;            // blank logit (elem 512)

  float m = xb;
#pragma unroll
  for (int k = 0; k < 8; ++k) m = fmaxf(m, v[k]);
#pragma unroll
  for (int off = 32; off; off >>= 1) m = fmaxf(m, __shfl_xor(m, off));
  float s = (l == 0) ? __expf(xb - m) : 0.f;
#pragma unroll
  for (int k = 0; k < 8; ++k) s += __expf(v[k] - m);
#pragma unroll
  for (int off = 32; off; off >>= 1) s += __shfl_xor(s, off);
  const float lse = m + __logf(s);

  // duration log-softmax (uniform per wave; broadcast load)
  const float4 dv = *(const float4*)(da + ((long)r << 2));
  const float m4 = fmaxf(fmaxf(dv.x, dv.y), fmaxf(dv.z, dv.w));
  const float l4 = m4 + __logf(__expf(dv.x - m4) + __expf(dv.y - m4) +
                               __expf(dv.z - m4) + __expf(dv.w - m4));
  const float d0 = dv.x - l4, d1 = dv.y - l4, d2 = dv.z - l4, d3 = dv.w - l4;

  float4* PBD4 = (float4*)ws;
  float4* PYD4 = (float4*)(ws + OFF_PYD);

  const int tp = t + 4;
  const int ib = (b * TP + tp) * TDT_U1 + u;
  if (l == 0) {
    const float pb = xb - lse - SIG;
    PBD4[ib] = make_float4(pb + d0, pb + d1, pb + d2, pb + d3);
  }

  // target gather (exactly one lane owns it); static indices only
  const int tg = (u < TDT_U) ? tgt[b * TDT_U + u] : -1;
  bool own = false; float vt = 0.f;
#pragma unroll
  for (int k = 0; k < 8; ++k) if ((l + (k << 6)) == tg) { vt = v[k]; own = true; }
  if (own) {
    const float py = vt - lse - SIG;
    PYD4[(b * TP + tp) * TDT_U + u] = make_float4(py + d0, py + d1, py + d2, py + d3);
  }

  // NEG pads for tau < 0 (slices tp = 0..3): lpX + ld = 2*NEG, matching ref lag pads
  if (t < 4) {
    const float nn = NEGV + NEGV;
    const float4 n4 = make_float4(nn, nn, nn, nn);
    if (l == 0) {
      PBD4[(b * TP + t) * TDT_U1 + u] = n4;
      if (u < TDT_U) PYD4[(b * TP + t) * TDT_U + u] = n4;
    }
  }
}

// Kernel 2: forward DP. One wave per b. Lane l owns alpha[.][l]; lane 63 also
// carries the u=64 column (c regs). 15-slot register FIFO, 12-step lookahead;
// 255 steps = 17 x unroll-15 so all FIFO indices are compile-time constants.
__global__ __launch_bounds__(64, 1) void k_dp(
    const float* __restrict__ ws, float* __restrict__ llo)
{
  const int b = blockIdx.x;
  const int l = threadIdx.x;
  const float4* PBD4 = (const float4*)ws + (size_t)b * (TP * TDT_U1);
  const float4* PYD4 = (const float4*)(ws + OFF_PYD) + (size_t)b * (TP * TDT_U);

  float4 fbd[15], fyd[15], f6d[15];

#define LOADS(slot, tpi) do {                      \
    fbd[slot] = PBD4[(tpi) * TDT_U1 + l];          \
    fyd[slot] = PYD4[(tpi) * TDT_U  + l];          \
    f6d[slot] = PBD4[(tpi) * TDT_U1 + 64];         \
  } while (0)

#pragma unroll
  for (int j = 1; j <= 15; ++j) LOADS(j % 15, j);

  float a1 = (l == 0) ? 0.f : NEGV, a2 = NEGV, a3 = NEGV, a4 = NEGV; // alpha[t-1..t-4][l]
  float c1 = NEGV, c2 = NEGV, c3 = NEGV, c4 = NEGV;                  // alpha[t-1..t-4][64]

  for (int tb = 1; tb < 256; tb += 15) {
#pragma unroll
    for (int k = 0; k < 15; ++k) {
      const int t  = tb + k;
      const int s0 = (k + 4) % 15, s1 = (k + 3) % 15,
                s2 = (k + 2) % 15, s3 = (k + 1) % 15;
      // term i: duration d=i+1, slice tp = t+3-i (slot s_i), ld component i
      const float blank = lse4(a1 + fbd[s0].x, a2 + fbd[s1].y,
                               a3 + fbd[s2].z, a4 + fbd[s3].w);
      const float label = lse4(a1 + fyd[s0].x, a2 + fyd[s1].y,
                               a3 + fyd[s2].z, a4 + fyd[s3].w);
      const float lprev = __shfl_up(label, 1);
      const float anew  = (l == 0) ? blank : lae(blank, lprev);
      // u = 64 column (valid on lane 63; harmless elsewhere)
      const float b64 = lse4(c1 + f6d[s0].x, c2 + f6d[s1].y,
                             c3 + f6d[s2].z, c4 + f6d[s3].w);
      const float cnew = lae(b64, label);
      a4 = a3; a3 = a2; a2 = a1; a1 = anew;
      c4 = c3; c3 = c2; c2 = c1; c1 = cnew;
      LOADS(s3, t + 15);   // slot (t+15)%15 == s3; slack slices cover t+15 > 259
    }
  }

  if (l == 63) {
    // ll = LSE_i( alpha[T-d][64] + lpb[T-d,64] + ld[T-d,64,i] ), tp = 259-i
    const float t0 = c1 + PBD4[259 * TDT_U1 + 64].x;
    const float t1 = c2 + PBD4[258 * TDT_U1 + 64].y;
    const float t2 = c3 + PBD4[257 * TDT_U1 + 64].z;
    const float t3 = c4 + PBD4[256 * TDT_U1 + 64].w;
    llo[b] = lse4(t0, t1, t2, t3);
  }
#undef LOADS
}

// Kernel 3: out = mean(-ll)
__global__ __launch_bounds__(64) void k_fin(
    const float* __restrict__ ll, float* __restrict__ out)
{
  const int l = threadIdx.x;
  float v = (l < TDT_B) ? ll[l] : 0.f;
#pragma unroll
  for (int off = 4; off; off >>= 1) v += __shfl_xor(v, off);
  if (l == 0) out[0] = -v * (1.0f / TDT_B);
}

extern "C" void kernel_launch(void* const* d_in, const int* in_sizes, int n_in,
                              void* d_out, int out_size, void* d_ws, size_t ws_size,
                              hipStream_t stream)
{
  const float* la = (const float*)d_in[0];   // label_acts    (B,T,U+1,V+1) f32
  const float* da = (const float*)d_in[1];   // duration_acts (B,T,U+1,D)   f32
  const int*   tg = (const int*)d_in[2];     // targets       (B,U)         i32
  float* ws  = (float*)d_ws;
  float* out = (float*)d_out;

  const int rows = TDT_B * TDT_T * TDT_U1;   // 133120
  k_prep<<<rows / 4, 256, 0, stream>>>(la, da, tg, ws);
  k_dp  <<<TDT_B, 64, 0, stream>>>(ws, ws + OFF_LL);
  k_fin <<<1, 64, 0, stream>>>(ws + OFF_LL, out);
}

// Round 2
// 136.918 us; speedup vs baseline: 1.2961x; 1.2961x over previous
//
#include <hip/hip_runtime.h>

// TDT loss, fixed shapes from setup_inputs():
#define TDT_B  8
#define TDT_T  256
#define TDT_U  64
#define TDT_U1 65
#define TDT_V1 513   // V+1, blank index = 512
#define TP     275   // 4 NEG pad slices + 256 + FIFO slack
#define NEGV  (-1e30f)
#define SIG    0.05f

// ws layout (floats):
//   PBD: float4[B][TP][U1]  = lpb(b,tau,u) + ld(b,tau,u,i)   (i in .x..w)
//   PYD: float4[B][TP][U]   = lpy(b,tau,u) + ld(b,tau,u,i)
#define OFF_PYD (TDT_B * TP * TDT_U1 * 4)            // 572000
#define OFF_LL  (OFF_PYD + TDT_B * TP * TDT_U * 4)   // (unused now)

__device__ __forceinline__ float lse4(float x0, float x1, float x2, float x3) {
  float m = fmaxf(fmaxf(x0, x1), fmaxf(x2, x3));
  float s = __expf(x0 - m) + __expf(x1 - m) + __expf(x2 - m) + __expf(x3 - m);
  return m + __logf(s);
}
__device__ __forceinline__ float lse8(float x0, float x1, float x2, float x3,
                                      float x4, float x5, float x6, float x7) {
  float ma = fmaxf(fmaxf(x0, x1), fmaxf(x2, x3));
  float mb = fmaxf(fmaxf(x4, x5), fmaxf(x6, x7));
  float m  = fmaxf(ma, mb);
  float s = __expf(x0 - m) + __expf(x1 - m) + __expf(x2 - m) + __expf(x3 - m)
          + __expf(x4 - m) + __expf(x5 - m) + __expf(x6 - m) + __expf(x7 - m);
  return m + __logf(s);
}

// Kernel 1: per-(b,t,u) row log-softmax over 513 labels (wave per row, float2
// loads with odd-row alignment shim), duration log-softmax over 4, write
// combined PBD/PYD float4 records. Also zero-inits out[0] for k_dp's atomics.
__global__ __launch_bounds__(256) void k_prep(
    const float* __restrict__ la, const float* __restrict__ da,
    const int* __restrict__ tgt, float* __restrict__ ws,
    float* __restrict__ out)
{
  if (blockIdx.x == 0 && threadIdx.x == 0) out[0] = 0.f;

  const int l = threadIdx.x & 63;
  const int r = (blockIdx.x << 2) + (threadIdx.x >> 6);   // row in [0, B*T*U1)
  const int u  = r % TDT_U1;
  const int bt = r / TDT_U1;
  const int t  = bt & (TDT_T - 1);
  const int b  = bt >> 8;

  const float* row = la + (size_t)r * TDT_V1;
  const int ofs = r & 1;                    // odd rows: shift by 1 for 8B align
  const float2* p2 = (const float2*)(row + ofs);
  float2 w[4];
#pragma unroll
  for (int k = 0; k < 4; ++k) w[k] = p2[l + (k << 6)];  // elems ofs+2l+128k+{0,1}
  const float extra = row[ofs ? 0 : 512];   // the one element outside the vec span

  float m = extra;
#pragma unroll
  for (int k = 0; k < 4; ++k) m = fmaxf(m, fmaxf(w[k].x, w[k].y));
#pragma unroll
  for (int off = 32; off; off >>= 1) m = fmaxf(m, __shfl_xor(m, off));
  float s = (l == 0) ? __expf(extra - m) : 0.f;
#pragma unroll
  for (int k = 0; k < 4; ++k) s += __expf(w[k].x - m) + __expf(w[k].y - m);
#pragma unroll
  for (int off = 32; off; off >>= 1) s += __shfl_xor(s, off);
  const float lse = m + __logf(s);

  // duration log-softmax (uniform per wave)
  const float4 dv = *(const float4*)(da + ((size_t)r << 2));
  const float m4 = fmaxf(fmaxf(dv.x, dv.y), fmaxf(dv.z, dv.w));
  const float l4 = m4 + __logf(__expf(dv.x - m4) + __expf(dv.y - m4) +
                               __expf(dv.z - m4) + __expf(dv.w - m4));
  const float d0 = dv.x - l4, d1 = dv.y - l4, d2 = dv.z - l4, d3 = dv.w - l4;

  float4* PBD4 = (float4*)ws;
  float4* PYD4 = (float4*)(ws + OFF_PYD);

  const int tp = t + 4;
  // blank logit = elem 512: ofs==0 -> extra (owner lane 0); ofs==1 -> w[3].y (lane 63)
  const float xb = ofs ? w[3].y : extra;
  if (l == (ofs ? 63 : 0)) {
    const float pb = xb - lse - SIG;
    PBD4[(b * TP + tp) * TDT_U1 + u] = make_float4(pb + d0, pb + d1, pb + d2, pb + d3);
  }

  // target gather (exactly one lane owns it); static indices only
  const int tg = (u < TDT_U) ? tgt[b * TDT_U + u] : -1;   // tg in [0,512)
  bool own = false; float vt = 0.f;
#pragma unroll
  for (int k = 0; k < 4; ++k) {
    const int base = ofs + ((l + (k << 6)) << 1);
    if (base == tg)     { vt = w[k].x; own = true; }
    if (base + 1 == tg) { vt = w[k].y; own = true; }
  }
  if (ofs && tg == 0 && l == 0) { vt = extra; own = true; }
  if (own) {
    const float py = vt - lse - SIG;
    PYD4[(b * TP + tp) * TDT_U + u] = make_float4(py + d0, py + d1, py + d2, py + d3);
  }

  // NEG pads for tau < 0 (slices tp = 0..3): lpX + ld = 2*NEG, matching ref lag pads
  if (t < 4 && l == 0) {
    const float nn = NEGV + NEGV;
    const float4 n4 = make_float4(nn, nn, nn, nn);
    PBD4[(b * TP + t) * TDT_U1 + u] = n4;
    if (u < TDT_U) PYD4[(b * TP + t) * TDT_U + u] = n4;
  }
}

// Kernel 2: forward DP. One wave per b. Lane l owns alpha[.][l]; the u=64
// column rides the c-regs (lane 63's view is the real one). 15-slot FIFO of
// NAMED float4 scalars (no arrays -> provably registers), 12-step lookahead.
// Per step: one lse8 for alpha (blank terms + shfl'd raw label terms) and one
// lse8 for the u=64 column. Result accumulated into out[0] via atomicAdd.
__global__ __launch_bounds__(64, 1) void k_dp(
    const float* __restrict__ ws, float* __restrict__ out)
{
  const int b = blockIdx.x;
  const int l = threadIdx.x;
  const float4* PBD4 = (const float4*)ws + (size_t)b * (TP * TDT_U1);
  const float4* PYD4 = (const float4*)(ws + OFF_PYD) + (size_t)b * (TP * TDT_U);

  float4 B0,B1,B2,B3,B4,B5,B6,B7,B8,B9,B10,B11,B12,B13,B14;
  float4 Y0,Y1,Y2,Y3,Y4,Y5,Y6,Y7,Y8,Y9,Y10,Y11,Y12,Y13,Y14;
  float4 G0,G1,G2,G3,G4,G5,G6,G7,G8,G9,G10,G11,G12,G13,G14;

#define LOADSLOT(S, tpi) do {                \
    const int _tp = (tpi);                   \
    B##S = PBD4[_tp * TDT_U1 + l];           \
    Y##S = PYD4[_tp * TDT_U  + l];           \
    G##S = PBD4[_tp * TDT_U1 + 64];          \
  } while (0)

  // preload slices 1..15 into slots (slice % 15)
  LOADSLOT(1, 1);  LOADSLOT(2, 2);  LOADSLOT(3, 3);  LOADSLOT(4, 4);
  LOADSLOT(5, 5);  LOADSLOT(6, 6);  LOADSLOT(7, 7);  LOADSLOT(8, 8);
  LOADSLOT(9, 9);  LOADSLOT(10,10); LOADSLOT(11,11); LOADSLOT(12,12);
  LOADSLOT(13,13); LOADSLOT(14,14); LOADSLOT(0, 15);

  float a1 = (l == 0) ? 0.f : NEGV, a2 = NEGV, a3 = NEGV, a4 = NEGV;
  float c1 = NEGV, c2 = NEGV, c3 = NEGV, c4 = NEGV;

  // step t: slot(t+3).x/.y/.z/.w hold slices t+3,t+2,t+1,t (durations 1..4)
#define STEP(S0,S1,S2,S3, TPL) do {                                          \
    float ly0 = a1 + Y##S0.x, ly1 = a2 + Y##S1.y,                            \
          ly2 = a3 + Y##S2.z, ly3 = a4 + Y##S3.w;                            \
    float m0 = __shfl_up(ly0, 1), m1 = __shfl_up(ly1, 1),                    \
          m2 = __shfl_up(ly2, 1), m3 = __shfl_up(ly3, 1);                    \
    if (l == 0) { m0 = NEGV; m1 = NEGV; m2 = NEGV; m3 = NEGV; }              \
    float n0 = a1 + B##S0.x, n1 = a2 + B##S1.y,                              \
          n2 = a3 + B##S2.z, n3 = a4 + B##S3.w;                              \
    float q0 = c1 + G##S0.x, q1 = c2 + G##S1.y,                              \
          q2 = c3 + G##S2.z, q3 = c4 + G##S3.w;                              \
    float anew = lse8(n0, n1, n2, n3, m0, m1, m2, m3);                       \
    float cnew = lse8(q0, q1, q2, q3, ly0, ly1, ly2, ly3);                   \
    a4 = a3; a3 = a2; a2 = a1; a1 = anew;                                    \
    c4 = c3; c3 = c2; c2 = c1; c1 = cnew;                                    \
    LOADSLOT(S3, TPL);                                                       \
  } while (0)

  for (int tb = 1; tb < 256; tb += 15) {
    STEP(4,3,2,1,    tb + 15);
    STEP(5,4,3,2,    tb + 16);
    STEP(6,5,4,3,    tb + 17);
    STEP(7,6,5,4,    tb + 18);
    STEP(8,7,6,5,    tb + 19);
    STEP(9,8,7,6,    tb + 20);
    STEP(10,9,8,7,   tb + 21);
    STEP(11,10,9,8,  tb + 22);
    STEP(12,11,10,9, tb + 23);
    STEP(13,12,11,10,tb + 24);
    STEP(14,13,12,11,tb + 25);
    STEP(0,14,13,12, tb + 26);
    STEP(1,0,14,13,  tb + 27);
    STEP(2,1,0,14,   tb + 28);
    STEP(3,2,1,0,    tb + 29);
  }

  if (l == 63) {
    // ll = LSE_i( alpha[256-d][64] + lpb[256-d,64] + ld[256-d,64,i] ), tp = 259-i
    const float t0 = c1 + PBD4[259 * TDT_U1 + 64].x;
    const float t1 = c2 + PBD4[258 * TDT_U1 + 64].y;
    const float t2 = c3 + PBD4[257 * TDT_U1 + 64].z;
    const float t3 = c4 + PBD4[256 * TDT_U1 + 64].w;
    const float ll = lse4(t0, t1, t2, t3);
    atomicAdd(out, ll * (-1.0f / TDT_B));
  }
#undef STEP
#undef LOADSLOT
}

extern "C" void kernel_launch(void* const* d_in, const int* in_sizes, int n_in,
                              void* d_out, int out_size, void* d_ws, size_t ws_size,
                              hipStream_t stream)
{
  const float* la = (const float*)d_in[0];   // label_acts    (B,T,U+1,V+1) f32
  const float* da = (const float*)d_in[1];   // duration_acts (B,T,U+1,D)   f32
  const int*   tg = (const int*)d_in[2];     // targets       (B,U)         i32
  float* ws  = (float*)d_ws;
  float* out = (float*)d_out;

  const int rows = TDT_B * TDT_T * TDT_U1;   // 133120
  k_prep<<<rows / 4, 256, 0, stream>>>(la, da, tg, ws, out);
  k_dp  <<<TDT_B, 64, 0, stream>>>(ws, out);
}